// Round 8
// baseline (309.796 us; speedup 1.0000x reference)
//
#include <hip/hip_runtime.h>

#define HH 1024
#define WW 1024
#define CG_STEPS 50
#define NB 256        // one block per CU; each block owns 4 grid rows
#define NT 1024       // one thread per column

#define SCOPE __HIP_MEMORY_SCOPE_AGENT
#define POISON64 0xAAAAAAAAAAAAAAAAULL

__device__ __forceinline__ float aload(const float* p) {
    return __hip_atomic_load(p, __ATOMIC_RELAXED, SCOPE);
}
__device__ __forceinline__ void astore(float* p, float v) {
    __hip_atomic_store(p, v, __ATOMIC_RELAXED, SCOPE);
}
__device__ __forceinline__ int iload(const int* p) {
    return __hip_atomic_load(p, __ATOMIC_RELAXED, SCOPE);
}
__device__ __forceinline__ void istore(int* p, int v) {
    __hip_atomic_store(p, v, __ATOMIC_RELAXED, SCOPE);
}
__device__ __forceinline__ unsigned long long uload(const unsigned long long* p) {
    return __hip_atomic_load(p, __ATOMIC_RELAXED, SCOPE);
}
__device__ __forceinline__ void ustore(unsigned long long* p, unsigned long long v) {
    __hip_atomic_store(p, v, __ATOMIC_RELAXED, SCOPE);
}

// ---- consume reduction k: EVERY wave independently polls all NB packed
// partials (4 coalesced u64 loads per lane) and xor-butterfly sums — no
// barriers, no LDS, bitwise-identical result in every lane/wave.
// rs >= 0 => low-word sign bit 0 => a real value never bit-equals poison.
__device__ __forceinline__ void consumeRedWave(const unsigned long long* red,
                                               int k, float& o1, float& o2) {
    const int lane = threadIdx.x & 63;
    const unsigned long long* basep = red + (size_t)k * NB;
    unsigned long long v[4];
    #pragma unroll
    for (int m = 0; m < 4; ++m) v[m] = uload(basep + m * 64 + lane);
    while (v[0] == POISON64 || v[1] == POISON64 ||
           v[2] == POISON64 || v[3] == POISON64) {
        __builtin_amdgcn_s_sleep(1);
        #pragma unroll
        for (int m = 0; m < 4; ++m)
            if (v[m] == POISON64) v[m] = uload(basep + m * 64 + lane);
    }
    float a = 0.f, b = 0.f;
    #pragma unroll
    for (int m = 0; m < 4; ++m) {
        a += __uint_as_float((unsigned)(v[m] & 0xFFFFFFFFu));
        b += __uint_as_float((unsigned)(v[m] >> 32));
    }
    #pragma unroll
    for (int mask = 1; mask < 64; mask <<= 1) {
        a += __shfl_xor(a, mask, 64);
        b += __shfl_xor(b, mask, 64);
    }
    o1 = a; o2 = b;
}

__global__ __launch_bounds__(NT)
void cgsolve_kernel(const int* __restrict__ cols, const float* __restrict__ vals,
                    const float* __restrict__ b, float* __restrict__ xout,
                    float* __restrict__ rbuf, unsigned long long* __restrict__ red,
                    int* __restrict__ flags) {
    const int col = threadIdx.x;
    const int bb  = blockIdx.x;

    __shared__ float sr[4][WW + 1];
    __shared__ float sa[16], sb[16];
    __shared__ int   scols[5 * WW];    // 5118 <= 5120
    __shared__ float svals[5 * WW];

    float adiag[4], art[4], alf[4], adn[4], awu[4];
    float x_[4], r_[4], w_[4], q_[4];
    float p_[4] = {0.f, 0.f, 0.f, 0.f};
    float s_[4] = {0.f, 0.f, 0.f, 0.f};
    float z_[4] = {0.f, 0.f, 0.f, 0.f};

    // ---- prologue: LDS-staged MATCHED COO parse (decode by col value —
    // no entry-order assumption), r = b, x = 0. Proven in rounds 5/6.
    for (int rr = 0; rr < 4; ++rr) {
        const int i    = 4 * bb + rr;
        const int off  = (i == 0) ? 0 : (4 * WW - 2) + (i - 1) * (5 * WW - 2);
        const int base = 1 + (i > 0) + (i < HH - 1);
        const int len  = base * WW + 2 * WW - 2;
        __syncthreads();
        for (int e = threadIdx.x; e < len; e += NT) {
            scols[e] = cols[off + e];
            svals[e] = vals[off + e];
        }
        __syncthreads();
        const int j      = col;
        const int within = (j == 0) ? 0 : (base + 1) + (j - 1) * (base + 2);
        const int nnz    = base + (j > 0) + (j < WW - 1);
        const int t      = i * WW + j;
        float dg = 0.f, wr = 0.f, wl = 0.f, wd = 0.f, wu = 0.f;
        #pragma unroll
        for (int e = 0; e < 5; ++e) {
            if (e < nnz) {
                const int   c = scols[within + e];
                const float v = svals[within + e];
                if (c == t)           dg = v;
                else if (c == t + 1)  wr = v;
                else if (c == t - 1)  wl = v;
                else if (c == t + WW) wd = v;
                else if (c == t - WW) wu = v;
            }
        }
        adiag[rr] = dg; art[rr] = wr; alf[rr] = wl; adn[rr] = wd; awu[rr] = wu;
        r_[rr] = b[t];
        x_[rr] = 0.f;
    }

    // post per-block partial k: wave xor-reduce -> LDS -> ONE barrier ->
    // lanes 0..15 finish -> lane 0 stores packed red + halo flag.
    // The barrier also (a) drains every wave's halo vmem stores so the flag
    // is safely ordered, and (b) fences sr/sa reuse across iterations.
    auto blockPartialPost = [&](int k, float a, float bfl, int flagval) {
        #pragma unroll
        for (int mask = 1; mask < 64; mask <<= 1) {
            a   += __shfl_xor(a,   mask, 64);
            bfl += __shfl_xor(bfl, mask, 64);
        }
        const int lane = threadIdx.x & 63, wid = threadIdx.x >> 6;
        if (lane == 0) { sa[wid] = a; sb[wid] = bfl; }
        __syncthreads();                       // barrier2
        if (threadIdx.x < 16) {
            float ta = sa[threadIdx.x], tb = sb[threadIdx.x];
            #pragma unroll
            for (int mask = 1; mask < 16; mask <<= 1) {
                ta += __shfl_xor(ta, mask, 16);
                tb += __shfl_xor(tb, mask, 16);
            }
            if (threadIdx.x == 0) {
                const unsigned long long v =
                    ((unsigned long long)__float_as_uint(tb) << 32) |
                    (unsigned long long)__float_as_uint(ta);
                ustore(&red[(size_t)k * NB + bb], v);
                istore(&flags[bb], flagval);
            }
        }
    };

    // ---- w0 = A r0 (halos straight from b); post halo0 + red0 + flag1 ----
    {
        #pragma unroll
        for (int rr = 0; rr < 4; ++rr) sr[rr][col] = r_[rr];
        __syncthreads();
        const float btop = (bb > 0)      ? b[(4 * bb - 1) * WW + col] : 0.f;
        const float bbot = (bb < NB - 1) ? b[(4 * bb + 4) * WW + col] : 0.f;
        float rs_l = 0.f, dl_l = 0.f;
        #pragma unroll
        for (int rr = 0; rr < 4; ++rr) {
            float sum = adiag[rr] * r_[rr];
            const float vr = (col < WW - 1) ? sr[rr][col + 1] : 0.f;
            const float vl = (col > 0)      ? sr[rr][col - 1] : 0.f;
            sum += art[rr] * vr + alf[rr] * vl;
            const float vd = (rr < 3) ? r_[rr + 1] : bbot;
            const float vu = (rr > 0) ? r_[rr - 1] : btop;
            sum += adn[rr] * vd + awu[rr] * vu;
            w_[rr] = sum;
            rs_l += r_[rr] * r_[rr];
            dl_l += sum * r_[rr];
        }
        astore(&rbuf[(2 * bb + 0) * WW + col], w_[0]);   // halo 0, buffer 0
        astore(&rbuf[(2 * bb + 1) * WW + col], w_[3]);
        blockPartialPost(0, rs_l, dl_l, 1);
    }

    float gamma_prev = 1.f, alpha_prev = 1.f;

    #pragma unroll 1
    for (int k = 0; k < CG_STEPS; ++k) {
        if (k < CG_STEPS - 1) {
            // stage w into LDS, poll neighbor halo-k flags, ONE barrier,
            // then read LDS + halos and compute q = A w.
            #pragma unroll
            for (int rr = 0; rr < 4; ++rr) sr[rr][col] = w_[rr];
            if (threadIdx.x == 0 && bb > 0)
                while (iload(&flags[bb - 1]) < k + 1) __builtin_amdgcn_s_sleep(1);
            if (threadIdx.x == 1 && bb < NB - 1)
                while (iload(&flags[bb + 1]) < k + 1) __builtin_amdgcn_s_sleep(1);
            __syncthreads();                   // barrier1
            const float* hb = rbuf + (size_t)(k & 1) * 2 * NB * WW;
            const float wtop = (bb > 0)
                ? aload(&hb[(2 * (bb - 1) + 1) * WW + col]) : 0.f;
            const float wbot = (bb < NB - 1)
                ? aload(&hb[(2 * (bb + 1) + 0) * WW + col]) : 0.f;
            #pragma unroll
            for (int rr = 0; rr < 4; ++rr) {
                float sum = adiag[rr] * w_[rr];
                const float vr = (col < WW - 1) ? sr[rr][col + 1] : 0.f;
                const float vl = (col > 0)      ? sr[rr][col - 1] : 0.f;
                sum += art[rr] * vr + alf[rr] * vl;
                const float vd = (rr < 3) ? w_[rr + 1] : wbot;
                const float vu = (rr > 0) ? w_[rr - 1] : wtop;
                sum += adn[rr] * vd + awu[rr] * vu;
                q_[rr] = sum;
            }
        }

        // consume reduction k (per-wave, barrier-free)
        float gam, del;
        consumeRedWave(red, k, gam, del);

        const float beta  = (k == 0) ? 0.f : gam / gamma_prev;
        const float alpha = (k == 0) ? gam / del
                                     : gam / (del - beta * gam / alpha_prev);
        #pragma unroll
        for (int rr = 0; rr < 4; ++rr) {
            p_[rr] = r_[rr] + beta * p_[rr];
            x_[rr] += alpha * p_[rr];
        }
        if (k == CG_STEPS - 1) break;

        float rs_l = 0.f, dl_l = 0.f;
        #pragma unroll
        for (int rr = 0; rr < 4; ++rr) {
            z_[rr] = q_[rr] + beta * z_[rr];
            s_[rr] = w_[rr] + beta * s_[rr];
            r_[rr] -= alpha * s_[rr];
            w_[rr] -= alpha * z_[rr];
            rs_l += r_[rr] * r_[rr];
            dl_l += w_[rr] * r_[rr];
        }
        // publish w-halo k+1 (double-buffered; race-free: we consumed red k,
        // so every block finished its iter-(k-1) reads of this buffer)
        float* hbn = rbuf + (size_t)((k + 1) & 1) * 2 * NB * WW;
        astore(&hbn[(2 * bb + 0) * WW + col], w_[0]);
        astore(&hbn[(2 * bb + 1) * WW + col], w_[3]);
        blockPartialPost(k + 1, rs_l, dl_l, k + 2);

        gamma_prev = gam; alpha_prev = alpha;
    }

    #pragma unroll
    for (int rr = 0; rr < 4; ++rr)
        xout[(4 * bb + rr) * WW + col] = x_[rr];
}

extern "C" void kernel_launch(void* const* d_in, const int* in_sizes, int n_in,
                              void* d_out, int out_size, void* d_ws, size_t ws_size,
                              hipStream_t stream) {
    const int*   cols = (const int*)d_in[1];
    const float* vals = (const float*)d_in[2];
    const float* b    = (const float*)d_in[3];
    float* x = (float*)d_out;

    float* w    = (float*)d_ws;
    float* rbuf = w;                                       // 2 bufs * 2*NB rows = 4 MB
    unsigned long long* red =
        (unsigned long long*)(rbuf + 2 * 2 * (size_t)NB * WW);  // CG_STEPS*NB u64
    int* flags = (int*)(red + (size_t)CG_STEPS * NB);      // NB ints

    // no memset: 0xAA poison is the sentinel for both red (sign-bit argument)
    // and flags (negative int < any k+1)

    void* args[] = {(void*)&cols, (void*)&vals, (void*)&b, (void*)&x,
                    (void*)&rbuf, (void*)&red, (void*)&flags};
    hipLaunchCooperativeKernel((void*)cgsolve_kernel, dim3(NB), dim3(NT),
                               args, 0, stream);
}

// Round 9
// 277.940 us; speedup vs baseline: 1.1146x; 1.1146x over previous
//
#include <hip/hip_runtime.h>

#define HH 1024
#define WW 1024
#define CG_STEPS 50
#define NB 256        // one block per CU; each block owns 4 grid rows
#define NT 1024       // one thread per column

#define SCOPE __HIP_MEMORY_SCOPE_AGENT
#define POISON64 0xAAAAAAAAAAAAAAAAULL

__device__ __forceinline__ float aload(const float* p) {
    return __hip_atomic_load(p, __ATOMIC_RELAXED, SCOPE);
}
__device__ __forceinline__ void astore(float* p, float v) {
    __hip_atomic_store(p, v, __ATOMIC_RELAXED, SCOPE);
}
__device__ __forceinline__ int iload(const int* p) {
    return __hip_atomic_load(p, __ATOMIC_RELAXED, SCOPE);
}
__device__ __forceinline__ void istore(int* p, int v) {
    __hip_atomic_store(p, v, __ATOMIC_RELAXED, SCOPE);
}
__device__ __forceinline__ unsigned long long uload(const unsigned long long* p) {
    return __hip_atomic_load(p, __ATOMIC_RELAXED, SCOPE);
}
__device__ __forceinline__ void ustore(unsigned long long* p, unsigned long long v) {
    __hip_atomic_store(p, v, __ATOMIC_RELAXED, SCOPE);
}

// ---- consume reduction k: EVERY wave independently polls all NB packed
// partials (4 coalesced u64 loads per lane) and xor-butterfly sums — no
// barriers, no LDS, bitwise-identical result in every lane/wave.
// rs >= 0 => low-word sign bit 0 => a real value never bit-equals poison.
__device__ __forceinline__ void consumeRedWave(const unsigned long long* red,
                                               int k, float& o1, float& o2) {
    const int lane = threadIdx.x & 63;
    const unsigned long long* basep = red + (size_t)k * NB;
    unsigned long long v[4];
    #pragma unroll
    for (int m = 0; m < 4; ++m) v[m] = uload(basep + m * 64 + lane);
    while (v[0] == POISON64 || v[1] == POISON64 ||
           v[2] == POISON64 || v[3] == POISON64) {
        __builtin_amdgcn_s_sleep(1);
        #pragma unroll
        for (int m = 0; m < 4; ++m)
            if (v[m] == POISON64) v[m] = uload(basep + m * 64 + lane);
    }
    float a = 0.f, b = 0.f;
    #pragma unroll
    for (int m = 0; m < 4; ++m) {
        a += __uint_as_float((unsigned)(v[m] & 0xFFFFFFFFu));
        b += __uint_as_float((unsigned)(v[m] >> 32));
    }
    #pragma unroll
    for (int mask = 1; mask < 64; mask <<= 1) {
        a += __shfl_xor(a, mask, 64);
        b += __shfl_xor(b, mask, 64);
    }
    o1 = a; o2 = b;
}

__global__ __launch_bounds__(NT)
void cgsolve_kernel(const int* __restrict__ cols, const float* __restrict__ vals,
                    const float* __restrict__ b, float* __restrict__ xout,
                    float* __restrict__ rbuf, unsigned long long* __restrict__ red,
                    int* __restrict__ flags) {
    const int col = threadIdx.x;
    const int bb  = blockIdx.x;

    __shared__ float sr[4][WW + 1];
    __shared__ float sa[16], sb[16];
    __shared__ int   scols[5 * WW];    // 5118 <= 5120
    __shared__ float svals[5 * WW];

    float adiag[4], art[4], alf[4], adn[4], awu[4];
    float x_[4], r_[4], w_[4], q_[4];
    float p_[4] = {0.f, 0.f, 0.f, 0.f};
    float s_[4] = {0.f, 0.f, 0.f, 0.f};
    float z_[4] = {0.f, 0.f, 0.f, 0.f};

    // ---- prologue: LDS-staged MATCHED COO parse (decode by col value —
    // no entry-order assumption), r = b, x = 0. Proven rounds 5/6/8.
    for (int rr = 0; rr < 4; ++rr) {
        const int i    = 4 * bb + rr;
        const int off  = (i == 0) ? 0 : (4 * WW - 2) + (i - 1) * (5 * WW - 2);
        const int base = 1 + (i > 0) + (i < HH - 1);
        const int len  = base * WW + 2 * WW - 2;
        __syncthreads();
        for (int e = threadIdx.x; e < len; e += NT) {
            scols[e] = cols[off + e];
            svals[e] = vals[off + e];
        }
        __syncthreads();
        const int j      = col;
        const int within = (j == 0) ? 0 : (base + 1) + (j - 1) * (base + 2);
        const int nnz    = base + (j > 0) + (j < WW - 1);
        const int t      = i * WW + j;
        float dg = 0.f, wr = 0.f, wl = 0.f, wd = 0.f, wu = 0.f;
        #pragma unroll
        for (int e = 0; e < 5; ++e) {
            if (e < nnz) {
                const int   c = scols[within + e];
                const float v = svals[within + e];
                if (c == t)           dg = v;
                else if (c == t + 1)  wr = v;
                else if (c == t - 1)  wl = v;
                else if (c == t + WW) wd = v;
                else if (c == t - WW) wu = v;
            }
        }
        adiag[rr] = dg; art[rr] = wr; alf[rr] = wl; adn[rr] = wd; awu[rr] = wu;
        r_[rr] = b[t];
        x_[rr] = 0.f;
    }

    // post per-block partial k: wave xor-reduce -> LDS -> ONE barrier ->
    // lanes 0..15 finish -> lane 0 stores packed red + halo flag.
    // The barrier also (a) drains every wave's halo vmem stores so the flag
    // is safely ordered, and (b) fences sr/sa reuse across iterations.
    auto blockPartialPost = [&](int k, float a, float bfl, int flagval) {
        #pragma unroll
        for (int mask = 1; mask < 64; mask <<= 1) {
            a   += __shfl_xor(a,   mask, 64);
            bfl += __shfl_xor(bfl, mask, 64);
        }
        const int lane = threadIdx.x & 63, wid = threadIdx.x >> 6;
        if (lane == 0) { sa[wid] = a; sb[wid] = bfl; }
        __syncthreads();                       // barrier2
        if (threadIdx.x < 16) {
            float ta = sa[threadIdx.x], tb = sb[threadIdx.x];
            #pragma unroll
            for (int mask = 1; mask < 16; mask <<= 1) {
                ta += __shfl_xor(ta, mask, 16);
                tb += __shfl_xor(tb, mask, 16);
            }
            if (threadIdx.x == 0) {
                const unsigned long long v =
                    ((unsigned long long)__float_as_uint(tb) << 32) |
                    (unsigned long long)__float_as_uint(ta);
                ustore(&red[(size_t)k * NB + bb], v);
                istore(&flags[bb], flagval);
            }
        }
    };

    // ---- w0 = A r0 (halos straight from b); post halo0 + red0 + flag1 ----
    {
        #pragma unroll
        for (int rr = 0; rr < 4; ++rr) sr[rr][col] = r_[rr];
        __syncthreads();
        const float btop = (bb > 0)      ? b[(4 * bb - 1) * WW + col] : 0.f;
        const float bbot = (bb < NB - 1) ? b[(4 * bb + 4) * WW + col] : 0.f;
        float rs_l = 0.f, dl_l = 0.f;
        #pragma unroll
        for (int rr = 0; rr < 4; ++rr) {
            float sum = adiag[rr] * r_[rr];
            const float vr = (col < WW - 1) ? sr[rr][col + 1] : 0.f;
            const float vl = (col > 0)      ? sr[rr][col - 1] : 0.f;
            sum += art[rr] * vr + alf[rr] * vl;
            const float vd = (rr < 3) ? r_[rr + 1] : bbot;
            const float vu = (rr > 0) ? r_[rr - 1] : btop;
            sum += adn[rr] * vd + awu[rr] * vu;
            w_[rr] = sum;
            rs_l += r_[rr] * r_[rr];
            dl_l += sum * r_[rr];
        }
        astore(&rbuf[(2 * bb + 0) * WW + col], w_[0]);   // halo 0, buffer 0
        astore(&rbuf[(2 * bb + 1) * WW + col], w_[3]);
        blockPartialPost(0, rs_l, dl_l, 1);
    }

    float gamma_prev = 1.f, alpha_prev = 1.f;

    #pragma unroll 1
    for (int k = 0; k < CG_STEPS; ++k) {
        if (k < CG_STEPS - 1) {
            // stage w into LDS, poll neighbor halo-k flags, ONE barrier,
            // then read LDS + halos and compute q = A w.
            #pragma unroll
            for (int rr = 0; rr < 4; ++rr) sr[rr][col] = w_[rr];
            if (threadIdx.x == 0 && bb > 0)
                while (iload(&flags[bb - 1]) < k + 1) __builtin_amdgcn_s_sleep(1);
            if (threadIdx.x == 1 && bb < NB - 1)
                while (iload(&flags[bb + 1]) < k + 1) __builtin_amdgcn_s_sleep(1);
            __syncthreads();                   // barrier1
            const float* hb = rbuf + (size_t)(k & 1) * 2 * NB * WW;
            const float wtop = (bb > 0)
                ? aload(&hb[(2 * (bb - 1) + 1) * WW + col]) : 0.f;
            const float wbot = (bb < NB - 1)
                ? aload(&hb[(2 * (bb + 1) + 0) * WW + col]) : 0.f;
            #pragma unroll
            for (int rr = 0; rr < 4; ++rr) {
                float sum = adiag[rr] * w_[rr];
                const float vr = (col < WW - 1) ? sr[rr][col + 1] : 0.f;
                const float vl = (col > 0)      ? sr[rr][col - 1] : 0.f;
                sum += art[rr] * vr + alf[rr] * vl;
                const float vd = (rr < 3) ? w_[rr + 1] : wbot;
                const float vu = (rr > 0) ? w_[rr - 1] : wtop;
                sum += adn[rr] * vd + awu[rr] * vu;
                q_[rr] = sum;
            }
        }

        // consume reduction k (per-wave, barrier-free)
        float gam, del;
        consumeRedWave(red, k, gam, del);

        const float beta  = (k == 0) ? 0.f : gam / gamma_prev;
        const float alpha = (k == 0) ? gam / del
                                     : gam / (del - beta * gam / alpha_prev);
        #pragma unroll
        for (int rr = 0; rr < 4; ++rr) {
            p_[rr] = r_[rr] + beta * p_[rr];
            x_[rr] += alpha * p_[rr];
        }
        if (k == CG_STEPS - 1) break;

        float rs_l = 0.f, dl_l = 0.f;
        #pragma unroll
        for (int rr = 0; rr < 4; ++rr) {
            z_[rr] = q_[rr] + beta * z_[rr];
            s_[rr] = w_[rr] + beta * s_[rr];
            r_[rr] -= alpha * s_[rr];
            w_[rr] -= alpha * z_[rr];
            rs_l += r_[rr] * r_[rr];
            dl_l += w_[rr] * r_[rr];
        }
        // publish w-halo k+1 (double-buffered; race-free: we consumed red k,
        // so every block finished its iter-(k-1) reads of this buffer)
        float* hbn = rbuf + (size_t)((k + 1) & 1) * 2 * NB * WW;
        astore(&hbn[(2 * bb + 0) * WW + col], w_[0]);
        astore(&hbn[(2 * bb + 1) * WW + col], w_[3]);
        blockPartialPost(k + 1, rs_l, dl_l, k + 2);

        gamma_prev = gam; alpha_prev = alpha;
    }

    #pragma unroll
    for (int rr = 0; rr < 4; ++rr)
        xout[(4 * bb + rr) * WW + col] = x_[rr];
}

extern "C" void kernel_launch(void* const* d_in, const int* in_sizes, int n_in,
                              void* d_out, int out_size, void* d_ws, size_t ws_size,
                              hipStream_t stream) {
    const int*   cols = (const int*)d_in[1];
    const float* vals = (const float*)d_in[2];
    const float* b    = (const float*)d_in[3];
    float* x = (float*)d_out;

    float* w    = (float*)d_ws;
    float* rbuf = w;                                       // 2 bufs * 2*NB rows = 4 MB
    unsigned long long* red =
        (unsigned long long*)(rbuf + 2 * 2 * (size_t)NB * WW);  // CG_STEPS*NB u64
    int* flags = (int*)(red + (size_t)CG_STEPS * NB);      // NB ints

    // no memset: 0xAA poison is the sentinel for both red (sign-bit argument)
    // and flags (negative int < any k+1).
    //
    // REGULAR launch (not cooperative): grid == 256 blocks == 256 CUs, 16
    // waves/CU @ 44 VGPR, 57 KB LDS < 160 KB -> every block is resident
    // before any can finish (they spin-wait on each other), so co-residency
    // holds by capacity. A/B test vs round 8: coop-launch overhead theory.
    cgsolve_kernel<<<dim3(NB), dim3(NT), 0, stream>>>(cols, vals, b, x,
                                                      rbuf, red, flags);
}

// Round 10
// 261.732 us; speedup vs baseline: 1.1836x; 1.0619x over previous
//
#include <hip/hip_runtime.h>

#define HH 1024
#define WW 1024
#define CG_STEPS 50
#define NB 256        // one block per CU; each block owns 4 grid rows
#define NT 1024       // one thread per column

#define SCOPE __HIP_MEMORY_SCOPE_AGENT
#define POISON64 0xAAAAAAAAAAAAAAAAULL

__device__ __forceinline__ float aload(const float* p) {
    return __hip_atomic_load(p, __ATOMIC_RELAXED, SCOPE);
}
__device__ __forceinline__ void astore(float* p, float v) {
    __hip_atomic_store(p, v, __ATOMIC_RELAXED, SCOPE);
}
__device__ __forceinline__ int iload(const int* p) {
    return __hip_atomic_load(p, __ATOMIC_RELAXED, SCOPE);
}
__device__ __forceinline__ void istore(int* p, int v) {
    __hip_atomic_store(p, v, __ATOMIC_RELAXED, SCOPE);
}
__device__ __forceinline__ unsigned long long uload(const unsigned long long* p) {
    return __hip_atomic_load(p, __ATOMIC_RELAXED, SCOPE);
}
__device__ __forceinline__ void ustore(unsigned long long* p, unsigned long long v) {
    __hip_atomic_store(p, v, __ATOMIC_RELAXED, SCOPE);
}

__global__ __launch_bounds__(NT)
void cgsolve_kernel(const int* __restrict__ cols, const float* __restrict__ vals,
                    const float* __restrict__ b, float* __restrict__ xout,
                    float* __restrict__ rbuf, unsigned long long* __restrict__ red,
                    int* __restrict__ flags) {
    const int col = threadIdx.x;
    const int bb  = blockIdx.x;

    __shared__ float sr[4][WW + 1];
    __shared__ float sa[16], sb[16];
    __shared__ float sg1, sg2;         // reduction-result broadcast slots
    __shared__ int   scols[5 * WW];    // 5118 <= 5120
    __shared__ float svals[5 * WW];

    float adiag[4], art[4], alf[4], adn[4], awu[4];
    float x_[4], r_[4], w_[4], q_[4];
    float p_[4] = {0.f, 0.f, 0.f, 0.f};
    float s_[4] = {0.f, 0.f, 0.f, 0.f};
    float z_[4] = {0.f, 0.f, 0.f, 0.f};

    // ---- prologue: LDS-staged MATCHED COO parse (decode by col value —
    // no entry-order assumption), r = b, x = 0. Proven rounds 5/6/8/9.
    for (int rr = 0; rr < 4; ++rr) {
        const int i    = 4 * bb + rr;
        const int off  = (i == 0) ? 0 : (4 * WW - 2) + (i - 1) * (5 * WW - 2);
        const int base = 1 + (i > 0) + (i < HH - 1);
        const int len  = base * WW + 2 * WW - 2;
        __syncthreads();
        for (int e = threadIdx.x; e < len; e += NT) {
            scols[e] = cols[off + e];
            svals[e] = vals[off + e];
        }
        __syncthreads();
        const int j      = col;
        const int within = (j == 0) ? 0 : (base + 1) + (j - 1) * (base + 2);
        const int nnz    = base + (j > 0) + (j < WW - 1);
        const int t      = i * WW + j;
        float dg = 0.f, wr = 0.f, wl = 0.f, wd = 0.f, wu = 0.f;
        #pragma unroll
        for (int e = 0; e < 5; ++e) {
            if (e < nnz) {
                const int   c = scols[within + e];
                const float v = svals[within + e];
                if (c == t)           dg = v;
                else if (c == t + 1)  wr = v;
                else if (c == t - 1)  wl = v;
                else if (c == t + WW) wd = v;
                else if (c == t - WW) wu = v;
            }
        }
        adiag[rr] = dg; art[rr] = wr; alf[rr] = wl; adn[rr] = wd; awu[rr] = wu;
        r_[rr] = b[t];
        x_[rr] = 0.f;
    }

    // ---- consume reduction k: ONLY WAVE 0 polls the 256 packed partials
    // (4 coalesced u64 loads/lane) and xor-butterfly sums; waves 1..15 wait
    // at the barrier. 16x less IF poll traffic than all-wave polling; the
    // summation order is identical to the all-wave version -> bit-identical
    // trajectory. rs >= 0 => low-word sign bit 0 => real value != poison.
    auto consumeRed = [&](int k, float& o1, float& o2) {
        if (threadIdx.x < 64) {
            const int lane = threadIdx.x;
            const unsigned long long* basep = red + (size_t)k * NB;
            unsigned long long v[4];
            #pragma unroll
            for (int m = 0; m < 4; ++m) v[m] = uload(basep + m * 64 + lane);
            while (v[0] == POISON64 || v[1] == POISON64 ||
                   v[2] == POISON64 || v[3] == POISON64) {
                __builtin_amdgcn_s_sleep(1);
                #pragma unroll
                for (int m = 0; m < 4; ++m)
                    if (v[m] == POISON64) v[m] = uload(basep + m * 64 + lane);
            }
            float a = 0.f, bb2 = 0.f;
            #pragma unroll
            for (int m = 0; m < 4; ++m) {
                a   += __uint_as_float((unsigned)(v[m] & 0xFFFFFFFFu));
                bb2 += __uint_as_float((unsigned)(v[m] >> 32));
            }
            #pragma unroll
            for (int mask = 1; mask < 64; mask <<= 1) {
                a   += __shfl_xor(a,   mask, 64);
                bb2 += __shfl_xor(bb2, mask, 64);
            }
            if (lane == 0) { sg1 = a; sg2 = bb2; }
        }
        __syncthreads();                       // barrier3 (broadcast)
        o1 = sg1; o2 = sg2;
        // sg reuse is safe: barrier2 (post) + barrier1 (stage) intervene
        // before the next consume's write.
    };

    // post per-block partial k: wave xor-reduce -> LDS -> ONE barrier ->
    // lanes 0..15 finish -> lane 0 stores packed red + halo flag.
    // The barrier also (a) drains every wave's halo vmem stores so the flag
    // is safely ordered, and (b) fences sr/sa reuse across iterations.
    auto blockPartialPost = [&](int k, float a, float bfl, int flagval) {
        #pragma unroll
        for (int mask = 1; mask < 64; mask <<= 1) {
            a   += __shfl_xor(a,   mask, 64);
            bfl += __shfl_xor(bfl, mask, 64);
        }
        const int lane = threadIdx.x & 63, wid = threadIdx.x >> 6;
        if (lane == 0) { sa[wid] = a; sb[wid] = bfl; }
        __syncthreads();                       // barrier2
        if (threadIdx.x < 16) {
            float ta = sa[threadIdx.x], tb = sb[threadIdx.x];
            #pragma unroll
            for (int mask = 1; mask < 16; mask <<= 1) {
                ta += __shfl_xor(ta, mask, 16);
                tb += __shfl_xor(tb, mask, 16);
            }
            if (threadIdx.x == 0) {
                const unsigned long long v =
                    ((unsigned long long)__float_as_uint(tb) << 32) |
                    (unsigned long long)__float_as_uint(ta);
                ustore(&red[(size_t)k * NB + bb], v);
                istore(&flags[bb], flagval);
            }
        }
    };

    // ---- w0 = A r0 (halos straight from b); post halo0 + red0 + flag1 ----
    {
        #pragma unroll
        for (int rr = 0; rr < 4; ++rr) sr[rr][col] = r_[rr];
        __syncthreads();
        const float btop = (bb > 0)      ? b[(4 * bb - 1) * WW + col] : 0.f;
        const float bbot = (bb < NB - 1) ? b[(4 * bb + 4) * WW + col] : 0.f;
        float rs_l = 0.f, dl_l = 0.f;
        #pragma unroll
        for (int rr = 0; rr < 4; ++rr) {
            float sum = adiag[rr] * r_[rr];
            const float vr = (col < WW - 1) ? sr[rr][col + 1] : 0.f;
            const float vl = (col > 0)      ? sr[rr][col - 1] : 0.f;
            sum += art[rr] * vr + alf[rr] * vl;
            const float vd = (rr < 3) ? r_[rr + 1] : bbot;
            const float vu = (rr > 0) ? r_[rr - 1] : btop;
            sum += adn[rr] * vd + awu[rr] * vu;
            w_[rr] = sum;
            rs_l += r_[rr] * r_[rr];
            dl_l += sum * r_[rr];
        }
        astore(&rbuf[(2 * bb + 0) * WW + col], w_[0]);   // halo 0, buffer 0
        astore(&rbuf[(2 * bb + 1) * WW + col], w_[3]);
        blockPartialPost(0, rs_l, dl_l, 1);
    }

    float gamma_prev = 1.f, alpha_prev = 1.f;

    #pragma unroll 1
    for (int k = 0; k < CG_STEPS; ++k) {
        if (k < CG_STEPS - 1) {
            // stage w into LDS, poll neighbor halo-k flags, ONE barrier,
            // then read LDS + halos and compute q = A w.
            #pragma unroll
            for (int rr = 0; rr < 4; ++rr) sr[rr][col] = w_[rr];
            if (threadIdx.x == 0 && bb > 0)
                while (iload(&flags[bb - 1]) < k + 1) __builtin_amdgcn_s_sleep(1);
            if (threadIdx.x == 1 && bb < NB - 1)
                while (iload(&flags[bb + 1]) < k + 1) __builtin_amdgcn_s_sleep(1);
            __syncthreads();                   // barrier1
            const float* hb = rbuf + (size_t)(k & 1) * 2 * NB * WW;
            const float wtop = (bb > 0)
                ? aload(&hb[(2 * (bb - 1) + 1) * WW + col]) : 0.f;
            const float wbot = (bb < NB - 1)
                ? aload(&hb[(2 * (bb + 1) + 0) * WW + col]) : 0.f;
            #pragma unroll
            for (int rr = 0; rr < 4; ++rr) {
                float sum = adiag[rr] * w_[rr];
                const float vr = (col < WW - 1) ? sr[rr][col + 1] : 0.f;
                const float vl = (col > 0)      ? sr[rr][col - 1] : 0.f;
                sum += art[rr] * vr + alf[rr] * vl;
                const float vd = (rr < 3) ? w_[rr + 1] : wbot;
                const float vu = (rr > 0) ? w_[rr - 1] : wtop;
                sum += adn[rr] * vd + awu[rr] * vu;
                q_[rr] = sum;
            }
        }

        // consume reduction k (wave-0 poll + LDS broadcast)
        float gam, del;
        consumeRed(k, gam, del);

        const float beta  = (k == 0) ? 0.f : gam / gamma_prev;
        const float alpha = (k == 0) ? gam / del
                                     : gam / (del - beta * gam / alpha_prev);
        #pragma unroll
        for (int rr = 0; rr < 4; ++rr) {
            p_[rr] = r_[rr] + beta * p_[rr];
            x_[rr] += alpha * p_[rr];
        }
        if (k == CG_STEPS - 1) break;

        float rs_l = 0.f, dl_l = 0.f;
        #pragma unroll
        for (int rr = 0; rr < 4; ++rr) {
            z_[rr] = q_[rr] + beta * z_[rr];
            s_[rr] = w_[rr] + beta * s_[rr];
            r_[rr] -= alpha * s_[rr];
            w_[rr] -= alpha * z_[rr];
            rs_l += r_[rr] * r_[rr];
            dl_l += w_[rr] * r_[rr];
        }
        // publish w-halo k+1 (double-buffered; race-free: we consumed red k,
        // so every block finished its iter-(k-1) reads of this buffer)
        float* hbn = rbuf + (size_t)((k + 1) & 1) * 2 * NB * WW;
        astore(&hbn[(2 * bb + 0) * WW + col], w_[0]);
        astore(&hbn[(2 * bb + 1) * WW + col], w_[3]);
        blockPartialPost(k + 1, rs_l, dl_l, k + 2);

        gamma_prev = gam; alpha_prev = alpha;
    }

    #pragma unroll
    for (int rr = 0; rr < 4; ++rr)
        xout[(4 * bb + rr) * WW + col] = x_[rr];
}

extern "C" void kernel_launch(void* const* d_in, const int* in_sizes, int n_in,
                              void* d_out, int out_size, void* d_ws, size_t ws_size,
                              hipStream_t stream) {
    const int*   cols = (const int*)d_in[1];
    const float* vals = (const float*)d_in[2];
    const float* b    = (const float*)d_in[3];
    float* x = (float*)d_out;

    float* w    = (float*)d_ws;
    float* rbuf = w;                                       // 2 bufs * 2*NB rows = 4 MB
    unsigned long long* red =
        (unsigned long long*)(rbuf + 2 * 2 * (size_t)NB * WW);  // CG_STEPS*NB u64
    int* flags = (int*)(red + (size_t)CG_STEPS * NB);      // NB ints

    // no memset: 0xAA poison is the sentinel for both red (sign-bit argument)
    // and flags (negative int < any k+1).
    //
    // Regular launch: 256 blocks on 256 CUs, 16 waves/CU @ 44 VGPR,
    // 57 KB LDS < 160 KB -> all blocks resident by capacity (verified R9).
    cgsolve_kernel<<<dim3(NB), dim3(NT), 0, stream>>>(cols, vals, b, x,
                                                      rbuf, red, flags);
}

// Round 14
// 258.125 us; speedup vs baseline: 1.2002x; 1.0140x over previous
//
#include <hip/hip_runtime.h>

#define HH 1024
#define WW 1024
#define CG_STEPS 50
#define NB 256        // one block per CU; each block owns 4 grid rows
#define NT 1024       // one thread per column (16 waves) — max legal block size

#define SCOPE __HIP_MEMORY_SCOPE_AGENT
#define POISON64 0xAAAAAAAAAAAAAAAAULL

__device__ __forceinline__ float aload(const float* p) {
    return __hip_atomic_load(p, __ATOMIC_RELAXED, SCOPE);
}
__device__ __forceinline__ void astore(float* p, float v) {
    __hip_atomic_store(p, v, __ATOMIC_RELAXED, SCOPE);
}
__device__ __forceinline__ int iload(const int* p) {
    return __hip_atomic_load(p, __ATOMIC_RELAXED, SCOPE);
}
__device__ __forceinline__ void istore(int* p, int v) {
    __hip_atomic_store(p, v, __ATOMIC_RELAXED, SCOPE);
}
__device__ __forceinline__ unsigned long long uload(const unsigned long long* p) {
    return __hip_atomic_load(p, __ATOMIC_RELAXED, SCOPE);
}
__device__ __forceinline__ void ustore(unsigned long long* p, unsigned long long v) {
    __hip_atomic_store(p, v, __ATOMIC_RELAXED, SCOPE);
}

__global__ __launch_bounds__(NT)
void cgsolve_kernel(const int* __restrict__ cols, const float* __restrict__ vals,
                    const float* __restrict__ b, float* __restrict__ xout,
                    float* __restrict__ rbuf, unsigned long long* __restrict__ red,
                    int* __restrict__ flags) {
    const int col = threadIdx.x;
    const int bb  = blockIdx.x;

    __shared__ float sr[4][WW + 1];
    __shared__ float sa[16], sb[16];
    __shared__ float sg1, sg2;         // reduction-result broadcast slots
    __shared__ int   scols[5 * WW];    // 5118 <= 5120
    __shared__ float svals[5 * WW];

    float adiag[4], art[4], alf[4], adn[4], awu[4];
    float x_[4], r_[4], w_[4], q_[4];
    float p_[4] = {0.f, 0.f, 0.f, 0.f};
    float s_[4] = {0.f, 0.f, 0.f, 0.f};
    float z_[4] = {0.f, 0.f, 0.f, 0.f};

    // ---- prologue: LDS-staged MATCHED COO parse (decode by col value —
    // no entry-order assumption), r = b, x = 0. Proven rounds 5/6/8/9/10.
    for (int rr = 0; rr < 4; ++rr) {
        const int i    = 4 * bb + rr;
        const int off  = (i == 0) ? 0 : (4 * WW - 2) + (i - 1) * (5 * WW - 2);
        const int base = 1 + (i > 0) + (i < HH - 1);
        const int len  = base * WW + 2 * WW - 2;
        __syncthreads();
        for (int e = threadIdx.x; e < len; e += NT) {
            scols[e] = cols[off + e];
            svals[e] = vals[off + e];
        }
        __syncthreads();
        const int j      = col;
        const int within = (j == 0) ? 0 : (base + 1) + (j - 1) * (base + 2);
        const int nnz    = base + (j > 0) + (j < WW - 1);
        const int t      = i * WW + j;
        float dg = 0.f, wr = 0.f, wl = 0.f, wd = 0.f, wu = 0.f;
        #pragma unroll
        for (int e = 0; e < 5; ++e) {
            if (e < nnz) {
                const int   c = scols[within + e];
                const float v = svals[within + e];
                if (c == t)           dg = v;
                else if (c == t + 1)  wr = v;
                else if (c == t - 1)  wl = v;
                else if (c == t + WW) wd = v;
                else if (c == t - WW) wu = v;
            }
        }
        adiag[rr] = dg; art[rr] = wr; alf[rr] = wl; adn[rr] = wd; awu[rr] = wu;
        r_[rr] = b[t];
        x_[rr] = 0.f;
    }

    // ---- consume reduction k: ONLY WAVE 0 polls the 256 packed partials
    // (4 coalesced u64 loads/lane) and xor-butterfly sums; waves 1..15 wait
    // at the barrier. Loads are issued INSIDE the poll loop (R13's pre-issue
    // variant tripped the nondeterminism tripwire — do not pre-issue).
    // rs >= 0 => low-word sign bit 0 => a real value never bit-equals poison.
    auto consumeRed = [&](int k, float& o1, float& o2) {
        if (threadIdx.x < 64) {
            const int lane = threadIdx.x;
            const unsigned long long* basep = red + (size_t)k * NB;
            unsigned long long v[4];
            #pragma unroll
            for (int m = 0; m < 4; ++m) v[m] = uload(basep + m * 64 + lane);
            while (v[0] == POISON64 || v[1] == POISON64 ||
                   v[2] == POISON64 || v[3] == POISON64) {
                __builtin_amdgcn_s_sleep(1);
                #pragma unroll
                for (int m = 0; m < 4; ++m)
                    if (v[m] == POISON64) v[m] = uload(basep + m * 64 + lane);
            }
            float a = 0.f, bb2 = 0.f;
            #pragma unroll
            for (int m = 0; m < 4; ++m) {
                a   += __uint_as_float((unsigned)(v[m] & 0xFFFFFFFFu));
                bb2 += __uint_as_float((unsigned)(v[m] >> 32));
            }
            #pragma unroll
            for (int mask = 1; mask < 64; mask <<= 1) {
                a   += __shfl_xor(a,   mask, 64);
                bb2 += __shfl_xor(bb2, mask, 64);
            }
            if (lane == 0) { sg1 = a; sg2 = bb2; }
        }
        __syncthreads();                       // barrier3 (broadcast)
        o1 = sg1; o2 = sg2;
        // sg reuse is safe: barrier2 (post) + barrier1 (stage) intervene
        // before the next consume's write.
    };

    // post per-block partial k: wave xor-reduce -> LDS -> ONE barrier ->
    // lanes 0..15 finish -> thread 0 stores packed red + halo flag.
    // The barrier also (a) drains every wave's halo vmem stores so the flag
    // is safely ordered, and (b) fences sr/sa/sg reuse across iterations.
    auto blockPartialPost = [&](int k, float a, float bfl, int flagval) {
        #pragma unroll
        for (int mask = 1; mask < 64; mask <<= 1) {
            a   += __shfl_xor(a,   mask, 64);
            bfl += __shfl_xor(bfl, mask, 64);
        }
        const int lane = threadIdx.x & 63, wid = threadIdx.x >> 6;
        if (lane == 0) { sa[wid] = a; sb[wid] = bfl; }
        __syncthreads();                       // barrier2
        if (threadIdx.x < 16) {
            float ta = sa[threadIdx.x], tb = sb[threadIdx.x];
            #pragma unroll
            for (int mask = 1; mask < 16; mask <<= 1) {
                ta += __shfl_xor(ta, mask, 16);
                tb += __shfl_xor(tb, mask, 16);
            }
            if (threadIdx.x == 0) {
                const unsigned long long v =
                    ((unsigned long long)__float_as_uint(tb) << 32) |
                    (unsigned long long)__float_as_uint(ta);
                ustore(&red[(size_t)k * NB + bb], v);
                istore(&flags[bb], flagval);
            }
        }
    };

    // ---- w0 = A r0 (halos straight from b); post halo0 + red0 + flag1 ----
    {
        #pragma unroll
        for (int rr = 0; rr < 4; ++rr) sr[rr][col] = r_[rr];
        __syncthreads();
        const float btop = (bb > 0)      ? b[(4 * bb - 1) * WW + col] : 0.f;
        const float bbot = (bb < NB - 1) ? b[(4 * bb + 4) * WW + col] : 0.f;
        float rs_l = 0.f, dl_l = 0.f;
        #pragma unroll
        for (int rr = 0; rr < 4; ++rr) {
            float sum = adiag[rr] * r_[rr];
            const float vr = (col < WW - 1) ? sr[rr][col + 1] : 0.f;
            const float vl = (col > 0)      ? sr[rr][col - 1] : 0.f;
            sum += art[rr] * vr + alf[rr] * vl;
            const float vd = (rr < 3) ? r_[rr + 1] : bbot;
            const float vu = (rr > 0) ? r_[rr - 1] : btop;
            sum += adn[rr] * vd + awu[rr] * vu;
            w_[rr] = sum;
            rs_l += r_[rr] * r_[rr];
            dl_l += sum * r_[rr];
        }
        astore(&rbuf[(2 * bb + 0) * WW + col], w_[0]);   // halo 0, buffer 0
        astore(&rbuf[(2 * bb + 1) * WW + col], w_[3]);
        blockPartialPost(0, rs_l, dl_l, 1);
    }

    float gamma_prev = 1.f, alpha_prev = 1.f;

    #pragma unroll 1
    for (int k = 0; k < CG_STEPS; ++k) {
        if (k < CG_STEPS - 1) {
            // stage w into LDS, poll neighbor halo-k flags, ONE barrier,
            // then read LDS + halos and compute q = A w.
            #pragma unroll
            for (int rr = 0; rr < 4; ++rr) sr[rr][col] = w_[rr];
            if (threadIdx.x == 0 && bb > 0)
                while (iload(&flags[bb - 1]) < k + 1) __builtin_amdgcn_s_sleep(1);
            if (threadIdx.x == 1 && bb < NB - 1)
                while (iload(&flags[bb + 1]) < k + 1) __builtin_amdgcn_s_sleep(1);
            __syncthreads();                   // barrier1
            const float* hb = rbuf + (size_t)(k & 1) * 2 * NB * WW;
            const float wtop = (bb > 0)
                ? aload(&hb[(2 * (bb - 1) + 1) * WW + col]) : 0.f;
            const float wbot = (bb < NB - 1)
                ? aload(&hb[(2 * (bb + 1) + 0) * WW + col]) : 0.f;
            #pragma unroll
            for (int rr = 0; rr < 4; ++rr) {
                float sum = adiag[rr] * w_[rr];
                const float vr = (col < WW - 1) ? sr[rr][col + 1] : 0.f;
                const float vl = (col > 0)      ? sr[rr][col - 1] : 0.f;
                sum += art[rr] * vr + alf[rr] * vl;
                const float vd = (rr < 3) ? w_[rr + 1] : wbot;
                const float vu = (rr > 0) ? w_[rr - 1] : wtop;
                sum += adn[rr] * vd + awu[rr] * vu;
                q_[rr] = sum;
            }
        }

        // consume reduction k (wave-0 poll + LDS broadcast)
        float gam, del;
        consumeRed(k, gam, del);

        const float beta  = (k == 0) ? 0.f : gam / gamma_prev;
        const float alpha = (k == 0) ? gam / del
                                     : gam / (del - beta * gam / alpha_prev);
        #pragma unroll
        for (int rr = 0; rr < 4; ++rr) {
            p_[rr] = r_[rr] + beta * p_[rr];
            x_[rr] += alpha * p_[rr];
        }
        if (k == CG_STEPS - 1) break;

        float rs_l = 0.f, dl_l = 0.f;
        #pragma unroll
        for (int rr = 0; rr < 4; ++rr) {
            z_[rr] = q_[rr] + beta * z_[rr];
            s_[rr] = w_[rr] + beta * s_[rr];
            r_[rr] -= alpha * s_[rr];
            w_[rr] -= alpha * z_[rr];
            rs_l += r_[rr] * r_[rr];
            dl_l += w_[rr] * r_[rr];
        }
        // publish w-halo k+1 (double-buffered; race-free: we consumed red k,
        // so every block finished its iter-(k-1) reads of this buffer)
        float* hbn = rbuf + (size_t)((k + 1) & 1) * 2 * NB * WW;
        astore(&hbn[(2 * bb + 0) * WW + col], w_[0]);
        astore(&hbn[(2 * bb + 1) * WW + col], w_[3]);
        blockPartialPost(k + 1, rs_l, dl_l, k + 2);

        gamma_prev = gam; alpha_prev = alpha;
    }

    #pragma unroll
    for (int rr = 0; rr < 4; ++rr)
        xout[(4 * bb + rr) * WW + col] = x_[rr];
}

extern "C" void kernel_launch(void* const* d_in, const int* in_sizes, int n_in,
                              void* d_out, int out_size, void* d_ws, size_t ws_size,
                              hipStream_t stream) {
    const int*   cols = (const int*)d_in[1];
    const float* vals = (const float*)d_in[2];
    const float* b    = (const float*)d_in[3];
    float* x = (float*)d_out;

    float* w    = (float*)d_ws;
    float* rbuf = w;                                       // 2 bufs * 2*NB rows = 4 MB
    unsigned long long* red =
        (unsigned long long*)(rbuf + 2 * 2 * (size_t)NB * WW);  // CG_STEPS*NB u64
    int* flags = (int*)(red + (size_t)CG_STEPS * NB);      // NB ints

    // no memset: 0xAA poison is the sentinel for both red (sign-bit argument)
    // and flags (negative int < any k+1).
    //
    // Regular launch: 256 blocks on 256 CUs, 16 waves/CU, 57 KB LDS -> all
    // blocks resident by capacity (PROVEN R9/R10). Known-bad variants:
    // R11 NT=1088 (illegal block size), R12 512-block (residency deadlock),
    // R13 pre-issued polls (tripwire nondeterminism). Do not revisit.
    cgsolve_kernel<<<dim3(NB), dim3(NT), 0, stream>>>(cols, vals, b, x,
                                                      rbuf, red, flags);
}

// Round 15
// 257.209 us; speedup vs baseline: 1.2044x; 1.0036x over previous
//
#include <hip/hip_runtime.h>

#define HH 1024
#define WW 1024
#define CG_STEPS 50
#define NB 256        // one block per CU; each block owns 4 grid rows
#define NT 1024       // one thread per column (16 waves) — max legal block size

#define SCOPE __HIP_MEMORY_SCOPE_AGENT
#define POISON64 0xAAAAAAAAAAAAAAAAULL

__device__ __forceinline__ float aload(const float* p) {
    return __hip_atomic_load(p, __ATOMIC_RELAXED, SCOPE);
}
__device__ __forceinline__ void astore(float* p, float v) {
    __hip_atomic_store(p, v, __ATOMIC_RELAXED, SCOPE);
}
__device__ __forceinline__ int iload(const int* p) {
    return __hip_atomic_load(p, __ATOMIC_RELAXED, SCOPE);
}
__device__ __forceinline__ void istore(int* p, int v) {
    __hip_atomic_store(p, v, __ATOMIC_RELAXED, SCOPE);
}
__device__ __forceinline__ unsigned long long uload(const unsigned long long* p) {
    return __hip_atomic_load(p, __ATOMIC_RELAXED, SCOPE);
}
__device__ __forceinline__ void ustore(unsigned long long* p, unsigned long long v) {
    __hip_atomic_store(p, v, __ATOMIC_RELAXED, SCOPE);
}

__global__ __launch_bounds__(NT)
void cgsolve_kernel(const int* __restrict__ cols, const float* __restrict__ vals,
                    const float* __restrict__ b, float* __restrict__ xout,
                    float* __restrict__ rbuf, unsigned long long* __restrict__ red,
                    int* __restrict__ flags) {
    const int col = threadIdx.x;
    const int bb  = blockIdx.x;

    __shared__ float sr[4][WW + 1];
    __shared__ float sa[16], sb[16];
    __shared__ float sg1, sg2;         // reduction-result broadcast slots
    __shared__ int   scols[2][5 * WW]; // two staged rows (5118 <= 5120 each)
    __shared__ float svals[2][5 * WW];

    float adiag[4], art[4], alf[4], adn[4], awu[4];
    float x_[4], r_[4], w_[4], q_[4];
    float p_[4] = {0.f, 0.f, 0.f, 0.f};
    float s_[4] = {0.f, 0.f, 0.f, 0.f};
    float z_[4] = {0.f, 0.f, 0.f, 0.f};

    // ---- prologue: LDS-staged MATCHED COO parse (decode by col value — no
    // entry-order assumption; R7's positional variant failed on HW). NEW in
    // R15: two rows staged per round (2 rounds, not 4) with int2/float2
    // vector loads. Alignment proof: row byte offset = 4*off with
    // off = 4094 + (i-1)*5118 (both even) -> 8-byte aligned; len always even.
    for (int half = 0; half < 2; ++half) {
        __syncthreads();                       // protect LDS reuse across rounds
        #pragma unroll
        for (int rr2 = 0; rr2 < 2; ++rr2) {
            const int i    = 4 * bb + 2 * half + rr2;
            const int off  = (i == 0) ? 0 : (4 * WW - 2) + (i - 1) * (5 * WW - 2);
            const int base = 1 + (i > 0) + (i < HH - 1);
            const int len2 = (base * WW + 2 * WW - 2) >> 1;   // int2 count
            const int2*   gc = (const int2*)(cols + off);
            const float2* gv = (const float2*)(vals + off);
            int2*   lc = (int2*)scols[rr2];
            float2* lv = (float2*)svals[rr2];
            for (int e = threadIdx.x; e < len2; e += NT) {
                lc[e] = gc[e];
                lv[e] = gv[e];
            }
        }
        __syncthreads();
        #pragma unroll
        for (int rr2 = 0; rr2 < 2; ++rr2) {
            const int rr     = 2 * half + rr2;
            const int i      = 4 * bb + rr;
            const int base   = 1 + (i > 0) + (i < HH - 1);
            const int j      = col;
            const int within = (j == 0) ? 0 : (base + 1) + (j - 1) * (base + 2);
            const int nnz    = base + (j > 0) + (j < WW - 1);
            const int t      = i * WW + j;
            float dg = 0.f, wr = 0.f, wl = 0.f, wd = 0.f, wu = 0.f;
            #pragma unroll
            for (int e = 0; e < 5; ++e) {
                if (e < nnz) {
                    const int   c = scols[rr2][within + e];
                    const float v = svals[rr2][within + e];
                    if (c == t)           dg = v;
                    else if (c == t + 1)  wr = v;
                    else if (c == t - 1)  wl = v;
                    else if (c == t + WW) wd = v;
                    else if (c == t - WW) wu = v;
                }
            }
            adiag[rr] = dg; art[rr] = wr; alf[rr] = wl; adn[rr] = wd; awu[rr] = wu;
            r_[rr] = b[t];
            x_[rr] = 0.f;
        }
    }

    // ---- consume reduction k: ONLY WAVE 0 polls the 256 packed partials
    // (4 coalesced u64 loads/lane) and xor-butterfly sums; waves 1..15 wait
    // at the barrier. Loads are issued INSIDE the poll loop (R13's pre-issue
    // variant tripped the nondeterminism tripwire — do not pre-issue).
    // rs >= 0 => low-word sign bit 0 => a real value never bit-equals poison.
    auto consumeRed = [&](int k, float& o1, float& o2) {
        if (threadIdx.x < 64) {
            const int lane = threadIdx.x;
            const unsigned long long* basep = red + (size_t)k * NB;
            unsigned long long v[4];
            #pragma unroll
            for (int m = 0; m < 4; ++m) v[m] = uload(basep + m * 64 + lane);
            while (v[0] == POISON64 || v[1] == POISON64 ||
                   v[2] == POISON64 || v[3] == POISON64) {
                __builtin_amdgcn_s_sleep(1);
                #pragma unroll
                for (int m = 0; m < 4; ++m)
                    if (v[m] == POISON64) v[m] = uload(basep + m * 64 + lane);
            }
            float a = 0.f, bb2 = 0.f;
            #pragma unroll
            for (int m = 0; m < 4; ++m) {
                a   += __uint_as_float((unsigned)(v[m] & 0xFFFFFFFFu));
                bb2 += __uint_as_float((unsigned)(v[m] >> 32));
            }
            #pragma unroll
            for (int mask = 1; mask < 64; mask <<= 1) {
                a   += __shfl_xor(a,   mask, 64);
                bb2 += __shfl_xor(bb2, mask, 64);
            }
            if (lane == 0) { sg1 = a; sg2 = bb2; }
        }
        __syncthreads();                       // barrier3 (broadcast)
        o1 = sg1; o2 = sg2;
        // sg reuse is safe: barrier2 (post) + barrier1 (stage) intervene
        // before the next consume's write.
    };

    // post per-block partial k: wave xor-reduce -> LDS -> ONE barrier ->
    // lanes 0..15 finish -> thread 0 stores packed red + halo flag.
    // The barrier also (a) drains every wave's halo vmem stores so the flag
    // is safely ordered, and (b) fences sr/sa/sg reuse across iterations.
    auto blockPartialPost = [&](int k, float a, float bfl, int flagval) {
        #pragma unroll
        for (int mask = 1; mask < 64; mask <<= 1) {
            a   += __shfl_xor(a,   mask, 64);
            bfl += __shfl_xor(bfl, mask, 64);
        }
        const int lane = threadIdx.x & 63, wid = threadIdx.x >> 6;
        if (lane == 0) { sa[wid] = a; sb[wid] = bfl; }
        __syncthreads();                       // barrier2
        if (threadIdx.x < 16) {
            float ta = sa[threadIdx.x], tb = sb[threadIdx.x];
            #pragma unroll
            for (int mask = 1; mask < 16; mask <<= 1) {
                ta += __shfl_xor(ta, mask, 16);
                tb += __shfl_xor(tb, mask, 16);
            }
            if (threadIdx.x == 0) {
                const unsigned long long v =
                    ((unsigned long long)__float_as_uint(tb) << 32) |
                    (unsigned long long)__float_as_uint(ta);
                ustore(&red[(size_t)k * NB + bb], v);
                istore(&flags[bb], flagval);
            }
        }
    };

    // ---- w0 = A r0 (halos straight from b); post halo0 + red0 + flag1 ----
    {
        #pragma unroll
        for (int rr = 0; rr < 4; ++rr) sr[rr][col] = r_[rr];
        __syncthreads();
        const float btop = (bb > 0)      ? b[(4 * bb - 1) * WW + col] : 0.f;
        const float bbot = (bb < NB - 1) ? b[(4 * bb + 4) * WW + col] : 0.f;
        float rs_l = 0.f, dl_l = 0.f;
        #pragma unroll
        for (int rr = 0; rr < 4; ++rr) {
            float sum = adiag[rr] * r_[rr];
            const float vr = (col < WW - 1) ? sr[rr][col + 1] : 0.f;
            const float vl = (col > 0)      ? sr[rr][col - 1] : 0.f;
            sum += art[rr] * vr + alf[rr] * vl;
            const float vd = (rr < 3) ? r_[rr + 1] : bbot;
            const float vu = (rr > 0) ? r_[rr - 1] : btop;
            sum += adn[rr] * vd + awu[rr] * vu;
            w_[rr] = sum;
            rs_l += r_[rr] * r_[rr];
            dl_l += sum * r_[rr];
        }
        astore(&rbuf[(2 * bb + 0) * WW + col], w_[0]);   // halo 0, buffer 0
        astore(&rbuf[(2 * bb + 1) * WW + col], w_[3]);
        blockPartialPost(0, rs_l, dl_l, 1);
    }

    float gamma_prev = 1.f, alpha_prev = 1.f;

    #pragma unroll 1
    for (int k = 0; k < CG_STEPS; ++k) {
        if (k < CG_STEPS - 1) {
            // stage w into LDS, poll neighbor halo-k flags, ONE barrier,
            // then read LDS + halos and compute q = A w.
            #pragma unroll
            for (int rr = 0; rr < 4; ++rr) sr[rr][col] = w_[rr];
            if (threadIdx.x == 0 && bb > 0)
                while (iload(&flags[bb - 1]) < k + 1) __builtin_amdgcn_s_sleep(1);
            if (threadIdx.x == 1 && bb < NB - 1)
                while (iload(&flags[bb + 1]) < k + 1) __builtin_amdgcn_s_sleep(1);
            __syncthreads();                   // barrier1
            const float* hb = rbuf + (size_t)(k & 1) * 2 * NB * WW;
            const float wtop = (bb > 0)
                ? aload(&hb[(2 * (bb - 1) + 1) * WW + col]) : 0.f;
            const float wbot = (bb < NB - 1)
                ? aload(&hb[(2 * (bb + 1) + 0) * WW + col]) : 0.f;
            #pragma unroll
            for (int rr = 0; rr < 4; ++rr) {
                float sum = adiag[rr] * w_[rr];
                const float vr = (col < WW - 1) ? sr[rr][col + 1] : 0.f;
                const float vl = (col > 0)      ? sr[rr][col - 1] : 0.f;
                sum += art[rr] * vr + alf[rr] * vl;
                const float vd = (rr < 3) ? w_[rr + 1] : wbot;
                const float vu = (rr > 0) ? w_[rr - 1] : wtop;
                sum += adn[rr] * vd + awu[rr] * vu;
                q_[rr] = sum;
            }
        }

        // consume reduction k (wave-0 poll + LDS broadcast)
        float gam, del;
        consumeRed(k, gam, del);

        const float beta  = (k == 0) ? 0.f : gam / gamma_prev;
        const float alpha = (k == 0) ? gam / del
                                     : gam / (del - beta * gam / alpha_prev);
        #pragma unroll
        for (int rr = 0; rr < 4; ++rr) {
            p_[rr] = r_[rr] + beta * p_[rr];
            x_[rr] += alpha * p_[rr];
        }
        if (k == CG_STEPS - 1) break;

        float rs_l = 0.f, dl_l = 0.f;
        #pragma unroll
        for (int rr = 0; rr < 4; ++rr) {
            z_[rr] = q_[rr] + beta * z_[rr];
            s_[rr] = w_[rr] + beta * s_[rr];
            r_[rr] -= alpha * s_[rr];
            w_[rr] -= alpha * z_[rr];
            rs_l += r_[rr] * r_[rr];
            dl_l += w_[rr] * r_[rr];
        }
        // publish w-halo k+1 (double-buffered; race-free: we consumed red k,
        // so every block finished its iter-(k-1) reads of this buffer)
        float* hbn = rbuf + (size_t)((k + 1) & 1) * 2 * NB * WW;
        astore(&hbn[(2 * bb + 0) * WW + col], w_[0]);
        astore(&hbn[(2 * bb + 1) * WW + col], w_[3]);
        blockPartialPost(k + 1, rs_l, dl_l, k + 2);

        gamma_prev = gam; alpha_prev = alpha;
    }

    #pragma unroll
    for (int rr = 0; rr < 4; ++rr)
        xout[(4 * bb + rr) * WW + col] = x_[rr];
}

extern "C" void kernel_launch(void* const* d_in, const int* in_sizes, int n_in,
                              void* d_out, int out_size, void* d_ws, size_t ws_size,
                              hipStream_t stream) {
    const int*   cols = (const int*)d_in[1];
    const float* vals = (const float*)d_in[2];
    const float* b    = (const float*)d_in[3];
    float* x = (float*)d_out;

    float* w    = (float*)d_ws;
    float* rbuf = w;                                       // 2 bufs * 2*NB rows = 4 MB
    unsigned long long* red =
        (unsigned long long*)(rbuf + 2 * 2 * (size_t)NB * WW);  // CG_STEPS*NB u64
    int* flags = (int*)(red + (size_t)CG_STEPS * NB);      // NB ints

    // no memset: 0xAA poison is the sentinel for both red (sign-bit argument)
    // and flags (negative int < any k+1).
    //
    // Regular launch: 256 blocks on 256 CUs, 16 waves/CU, ~98 KB LDS (<160)
    // -> 1 block/CU, all blocks resident by capacity (PROVEN R9/R10/R14).
    // Known-bad: R11 NT=1088 (illegal), R12 512-block (deadlock), R13
    // pre-issued polls (nondeterminism), R7 positional parse (wrong on HW).
    cgsolve_kernel<<<dim3(NB), dim3(NT), 0, stream>>>(cols, vals, b, x,
                                                      rbuf, red, flags);
}